// Round 3
// baseline (254.500 us; speedup 1.0000x reference)
//
#include <hip/hip_runtime.h>

#define HH 512
#define WW 512
#define NIMG 128                      // 16*8 channel-images
#define STRIP 8                       // output rows per wave task
#define SPI (HH / STRIP)              // 64 strips per image
#define NTASK (NIMG * SPI)            // 8192 wave tasks
#define BLOCK 256
#define WPB 4                         // waves per block
#define NBLK (NTASK / WPB)            // 2048 blocks
#define CPX (NBLK / 8)                // 256 blocks per XCD chunk
#define NTOTAL (16.0 * 8.0 * 512.0 * 512.0)

// Fused grey-opening(2x2) + MSE, single kernel.
// Lane owns cols [4i,4i+4) (A) and [256+4i,256+4i+4) (B): every float4 load
// is part of a fully-contiguous 1KB wave access. All 10 rows (20 loads,
// 20KB/wave) are burst-issued up front for max memory-level parallelism;
// consumption order == issue order so vmcnt waits peel one row at a time.
__global__ __launch_bounds__(BLOCK) void opening_fused(
    const float* __restrict__ x, float* __restrict__ partial,
    int* __restrict__ counter, float* __restrict__ out)
{
    // XCD-chunked swizzle (bijective: 2048 % 8 == 0): same-XCD blocks get
    // contiguous strips -> halo rows hit that XCD's L2.
    const int wb    = (blockIdx.x & 7) * CPX + (blockIdx.x >> 3);
    const int lane  = threadIdx.x & 63;
    const int wid   = wb * WPB + (threadIdx.x >> 6);
    const int img   = wid >> 6;        // / SPI
    const int strip = wid & (SPI - 1); // % SPI
    const int r0  = strip * STRIP;
    const bool bot = (strip == SPI - 1);

    const float* ib = x + (size_t)img * (HH * WW);
    const int cA = lane * 4;
    const int cB = 256 + lane * 4;

    // ---- burst-issue all 20 dwordx4 loads: slots 0..9 = rows r0-1 .. r0+8 (clamped)
    float R[10][8];
#pragma unroll
    for (int s = 0; s < 10; ++s) {
        int r = r0 - 1 + s;
        r = (r < 0) ? 0 : ((r > HH - 1) ? (HH - 1) : r);
        const float4 a = *(const float4*)(ib + (size_t)r * WW + cA);
        const float4 b = *(const float4*)(ib + (size_t)r * WW + cB);
        R[s][0] = a.x; R[s][1] = a.y; R[s][2] = a.z; R[s][3] = a.w;
        R[s][4] = b.x; R[s][5] = b.y; R[s][6] = b.z; R[s][7] = b.w;
    }

    // column-eroded row from slot s -> rc[10] (5 A cols + 5 B cols).
    // 4 rotate-shuffles + selects handle both lane edges and the A/B seam.
#define RCROW(s, rc)                                                        \
    do {                                                                    \
        const float a0 = R[s][0], a1 = R[s][1], a2 = R[s][2], a3 = R[s][3]; \
        const float b0 = R[s][4], b1 = R[s][5], b2 = R[s][6], b3 = R[s][7]; \
        float upA = __shfl(a3, (lane - 1) & 63);                            \
        if (lane == 0) upA = a0;                   /* left col clamp */     \
        const float dnA = __shfl((lane == 0) ? b0 : a0, (lane + 1) & 63);   \
        float upB = __shfl((lane == 63) ? a3 : b3, (lane - 1) & 63);        \
        const float dnB = __shfl(b0, (lane + 1) & 63);                      \
        rc[0] = fminf(upA, a0); rc[1] = fminf(a0, a1);                      \
        rc[2] = fminf(a1, a2);  rc[3] = fminf(a2, a3);                      \
        rc[4] = fminf(a3, dnA);                                             \
        rc[5] = fminf(upB, b0); rc[6] = fminf(b0, b1);                      \
        rc[7] = fminf(b1, b2);  rc[8] = fminf(b2, b3);                      \
        rc[9] = (lane == 63) ? rc[8] : fminf(b3, dnB); /* right col clamp */\
    } while (0)

    float rp[10], dp[8];
    float acc = 0.f;
    RCROW(0, rp);

    // slots s=1..8 hold x rows r0..r0+7. er(row r0+s-1)=min(rc[s-1],rc[s]);
    // d = col-dilated er; op(row m) = max(d(m), d(m+1)); emit at s>=2.
#pragma unroll
    for (int s = 1; s <= 8; ++s) {
        float rc[10];
        RCROW(s, rc);
        float er[10], d[8];
#pragma unroll
        for (int j = 0; j < 10; ++j) er[j] = fminf(rp[j], rc[j]);
#pragma unroll
        for (int j = 0; j < 4; ++j) {
            d[j]     = fmaxf(er[j], er[j + 1]);
            d[4 + j] = fmaxf(er[5 + j], er[6 + j]);
        }
        if (s >= 2) {
#pragma unroll
            for (int j = 0; j < 8; ++j) {
                const int col = (j < 4) ? j : j;  // A cols 0..3 -> R[.][0..3], B -> [4..7]
                const float op = fmaxf(dp[j], d[j]);
                const float df = R[s - 1][col + ((j < 4) ? 0 : 0)] - op;
                acc = fmaf(df, df, acc);
            }
        }
#pragma unroll
        for (int j = 0; j < 10; ++j) rp[j] = rc[j];
#pragma unroll
        for (int j = 0; j < 8; ++j) dp[j] = d[j];
    }

    // epilogue: emit op(row r0+7)
    if (!bot) {
        float rc[10];
        RCROW(9, rc);
        float er[10];
#pragma unroll
        for (int j = 0; j < 10; ++j) er[j] = fminf(rp[j], rc[j]);
#pragma unroll
        for (int j = 0; j < 8; ++j) {
            const float dj = (j < 4) ? fmaxf(er[j], er[j + 1]) : fmaxf(er[j + 1], er[j + 2]);
            const float df = R[8][j] - fmaxf(dp[j], dj);
            acc = fmaf(df, df, acc);
        }
    } else {
        // bottom row clamp: op(H-1) = d(H-1) = dp
#pragma unroll
        for (int j = 0; j < 8; ++j) {
            const float df = R[8][j] - dp[j];
            acc = fmaf(df, df, acc);
        }
    }
#undef RCROW

    // ---- deterministic block partial: wave shfl tree -> LDS -> fixed order
    __shared__ float wsum[WPB];
#pragma unroll
    for (int off = 32; off; off >>= 1) acc += __shfl_down(acc, off);
    if (lane == 0) wsum[threadIdx.x >> 6] = acc;
    __syncthreads();
    if (threadIdx.x == 0)
        partial[blockIdx.x] = (wsum[0] + wsum[1]) + (wsum[2] + wsum[3]);

    // ---- last-block-done final reduction (deterministic fixed-order f64 tree)
    __shared__ int isLast;
    __threadfence();                       // publish partial[] (agent scope)
    if (threadIdx.x == 0)
        isLast = (atomicAdd(counter, 1) == NBLK - 1);
    __syncthreads();
    if (isLast) {
        __threadfence();                   // acquire: see all partials
        __shared__ double sm[256];
        const int t = threadIdx.x;
        double s = 0.0;
#pragma unroll
        for (int i = 0; i < NBLK / 256; ++i) s += (double)partial[t + 256 * i];
        sm[t] = s;
        __syncthreads();
        for (int h = 128; h > 0; h >>= 1) {
            if (t < h) sm[t] += sm[t + h];
            __syncthreads();
        }
        if (t == 0) out[0] = (float)(sm[0] / NTOTAL);
    }
}

extern "C" void kernel_launch(void* const* d_in, const int* in_sizes, int n_in,
                              void* d_out, int out_size, void* d_ws, size_t ws_size,
                              hipStream_t stream)
{
    const float* x = (const float*)d_in[0];
    int* counter   = (int*)d_ws;                    // 4 B flag, zeroed per call
    float* partial = (float*)((char*)d_ws + 256);   // 2048 floats
    float* out     = (float*)d_out;

    hipMemsetAsync(counter, 0, sizeof(int), stream);
    opening_fused<<<NBLK, BLOCK, 0, stream>>>(x, partial, counter, out);
}

// Round 4
// 29.060 us; speedup vs baseline: 8.7576x; 8.7576x over previous
//
#include <hip/hip_runtime.h>

#define HH 512
#define WW 512
#define STRIP 16                       // output rows per wave task
#define SPI (HH / STRIP)               // 32 strips per image
#define NTASK (128 * SPI)              // 4096 wave tasks
#define BLOCK 256
#define WPB 4                          // waves per block
#define NBLK (NTASK / WPB)             // 1024 blocks = exactly 4/CU
#define NSLOT (STRIP + 2)              // 18 row slots (r0-1 .. r0+16)
#define DEPTH 2                        // prefetch depth (rows in flight)
#define NTOTAL (16.0 * 8.0 * 512.0 * 512.0)

// Grey opening (2x2 flat SE, scipy origin convention) fused with MSE partials.
// Lane owns cols [4i,4i+4) (A) and [256+4i,256+4i+4) (B). Column halos are
// loaded per-lane (x[c-1], x[c+4], image-clamped) -> ZERO cross-lane ops, pure
// per-lane dataflow. re[c]=min(x[c-1],x[c]); er=min(re_up,re); d[c]=max(er[c],
// er[c+1]) with er right-edge clamp; op(m)=max(d(m),d(m+1)); acc+=(x-op)^2.
__global__ __launch_bounds__(BLOCK, 4) void opening_partial(
    const float* __restrict__ x, float* __restrict__ partial)
{
    // XCD-chunked swizzle (bijective: 1024 % 8 == 0): neighbors share an L2.
    const int wb    = (blockIdx.x & 7) * (NBLK / 8) + (blockIdx.x >> 3);
    const int lane  = threadIdx.x & 63;
    const int wid   = wb * WPB + (threadIdx.x >> 6);
    const int img   = wid >> 5;          // / SPI
    const int strip = wid & (SPI - 1);
    const int r0    = strip * STRIP;
    const bool bot  = (strip == SPI - 1);

    const float* ib = x + (size_t)img * (HH * WW);
    const int cA  = lane * 4;
    const int cB  = 256 + lane * 4;
    const int cAm = (lane == 0) ? 0 : cA - 1;      // x left clamp (erosion pad)
    const int cBm = cB - 1;
    const int cAp = cA + 4;                        // always <= 256, valid
    const int cBp = (cB + 4 > WW - 1) ? (WW - 1) : (cB + 4);
    const bool rcl = (cB + 4 > WW - 1);            // dilation er right clamp

    // slot layout: [xm1, x0, x1, x2, x3, x4] per group
    float RA[NSLOT][6], RB[NSLOT][6];

#define LOADS(s, r)                                                       \
    do {                                                                  \
        const float* rowp = ib + (size_t)(r) * WW;                        \
        const float4 a4 = *(const float4*)(rowp + cA);                    \
        const float4 b4 = *(const float4*)(rowp + cB);                    \
        RA[s][0] = rowp[cAm]; RA[s][1] = a4.x; RA[s][2] = a4.y;           \
        RA[s][3] = a4.z;      RA[s][4] = a4.w; RA[s][5] = rowp[cAp];      \
        RB[s][0] = rowp[cBm]; RB[s][1] = b4.x; RB[s][2] = b4.y;           \
        RB[s][3] = b4.z;      RB[s][4] = b4.w; RB[s][5] = rowp[cBp];      \
    } while (0)

    // column-eroded row: rc[j] = min(x[c+j-1], x[c+j]); rc[9] dilation-clamped
#define RCROW(s, rc)                                                      \
    do {                                                                  \
        rc[0] = fminf(RA[s][0], RA[s][1]); rc[1] = fminf(RA[s][1], RA[s][2]); \
        rc[2] = fminf(RA[s][2], RA[s][3]); rc[3] = fminf(RA[s][3], RA[s][4]); \
        rc[4] = fminf(RA[s][4], RA[s][5]);                                \
        rc[5] = fminf(RB[s][0], RB[s][1]); rc[6] = fminf(RB[s][1], RB[s][2]); \
        rc[7] = fminf(RB[s][2], RB[s][3]); rc[8] = fminf(RB[s][3], RB[s][4]); \
        rc[9] = rcl ? rc[8] : fminf(RB[s][4], RB[s][5]);                  \
    } while (0)

#define CLAMPR(r) (((r) < 0) ? 0 : (((r) > HH - 1) ? (HH - 1) : (r)))

    float rp[10], dp[8];
    float acc = 0.f;

    // prologue: issue first DEPTH rows
#pragma unroll
    for (int s = 0; s < DEPTH; ++s) LOADS(s, CLAMPR(r0 - 1 + s));

    // main: iters 0..NSLOT-2; slot s = re row (r0-1+s)
#pragma unroll
    for (int s = 0; s < NSLOT - 1; ++s) {
        if (s + DEPTH < NSLOT) LOADS(s + DEPTH, CLAMPR(r0 - 1 + s + DEPTH));
        float rc[10];
        RCROW(s, rc);
        if (s == 0) {
#pragma unroll
            for (int j = 0; j < 10; ++j) rp[j] = rc[j];
        } else {
            float er[10], d[8];
#pragma unroll
            for (int j = 0; j < 10; ++j) er[j] = fminf(rp[j], rc[j]);
#pragma unroll
            for (int j = 0; j < 4; ++j) {
                d[j]     = fmaxf(er[j], er[j + 1]);          // A cols
                d[4 + j] = fmaxf(er[5 + j], er[6 + j]);      // B cols
            }
            if (s >= 2) {   // emit op(row r0+s-2); its x lives in slot s-1
#pragma unroll
                for (int j = 0; j < 4; ++j) {
                    const float oA = fmaxf(dp[j], d[j]);
                    const float oB = fmaxf(dp[4 + j], d[4 + j]);
                    const float fA = RA[s - 1][j + 1] - oA;
                    const float fB = RB[s - 1][j + 1] - oB;
                    acc = fmaf(fA, fA, acc);
                    acc = fmaf(fB, fB, acc);
                }
            }
#pragma unroll
            for (int j = 0; j < 10; ++j) rp[j] = rc[j];
#pragma unroll
            for (int j = 0; j < 8; ++j) dp[j] = d[j];
        }
    }

    // epilogue (s = NSLOT-1): emit op(row r0+STRIP-1)
    if (!bot) {
        float rc[10];
        RCROW(NSLOT - 1, rc);
        float er[10];
#pragma unroll
        for (int j = 0; j < 10; ++j) er[j] = fminf(rp[j], rc[j]);
#pragma unroll
        for (int j = 0; j < 4; ++j) {
            const float dA = fmaxf(er[j], er[j + 1]);
            const float dB = fmaxf(er[5 + j], er[6 + j]);
            const float fA = RA[NSLOT - 2][j + 1] - fmaxf(dp[j], dA);
            const float fB = RB[NSLOT - 2][j + 1] - fmaxf(dp[4 + j], dB);
            acc = fmaf(fA, fA, acc);
            acc = fmaf(fB, fB, acc);
        }
    } else {
        // image bottom: d(H) clamps to d(H-1) => op(H-1) = d(H-1) = dp
#pragma unroll
        for (int j = 0; j < 4; ++j) {
            const float fA = RA[NSLOT - 2][j + 1] - dp[j];
            const float fB = RB[NSLOT - 2][j + 1] - dp[4 + j];
            acc = fmaf(fA, fA, acc);
            acc = fmaf(fB, fB, acc);
        }
    }
#undef LOADS
#undef RCROW
#undef CLAMPR

    // deterministic block partial: wave shfl tree -> LDS -> fixed-order sum
    __shared__ float wsum[WPB];
#pragma unroll
    for (int off = 32; off; off >>= 1) acc += __shfl_down(acc, off);
    if (lane == 0) wsum[threadIdx.x >> 6] = acc;
    __syncthreads();
    if (threadIdx.x == 0)
        partial[blockIdx.x] = (wsum[0] + wsum[1]) + (wsum[2] + wsum[3]);
}

// Deterministic final reduction: 1024 partials, one 256-thread block, f64 tree.
__global__ __launch_bounds__(256) void reduce_final(
    const float* __restrict__ partial, float* __restrict__ out)
{
    __shared__ double sm[256];
    const int t = threadIdx.x;
    double s = 0.0;
#pragma unroll
    for (int i = 0; i < NBLK / 256; ++i) s += (double)partial[t + 256 * i];
    sm[t] = s;
    __syncthreads();
    for (int h = 128; h > 0; h >>= 1) {
        if (t < h) sm[t] += sm[t + h];
        __syncthreads();
    }
    if (t == 0) out[0] = (float)(sm[0] / NTOTAL);
}

extern "C" void kernel_launch(void* const* d_in, const int* in_sizes, int n_in,
                              void* d_out, int out_size, void* d_ws, size_t ws_size,
                              hipStream_t stream)
{
    const float* x = (const float*)d_in[0];
    float* partial = (float*)d_ws;     // NBLK floats = 4 KB scratch
    float* out = (float*)d_out;

    opening_partial<<<NBLK, BLOCK, 0, stream>>>(x, partial);
    reduce_final<<<1, 256, 0, stream>>>(partial, out);
}